// Round 1
// baseline (269.658 us; speedup 1.0000x reference)
//
#include <hip/hip_runtime.h>
#include <hip/hip_bf16.h>

// Problem: pooled = tanh(hs @ W^T + b); out0 = pooled[:,0]; out1 = span-means;
// out2 = zeros(N,S).  N=64, L=512, H=768, S=16. Inputs fp32, d_out fp32.
//
// R6: fuse the A fp32->bf16 conversion INTO the GEMM.
//  - A (hidden_states) is staged fp32 via global_load_lds and converted to
//    bf16 in-register at fragment-build time (v_cvt_pk_bf16_f32, RNE — same
//    numerics as the old convert pass). Kills the 150 MB convert round-trip.
//  - convert kernel now handles W only (2.4 MB -> 1.2 MB, ~1 us).
//  - Both-sides LDS XOR swizzle (linear gload_lds dest + inverse-swizzled
//    global source + swizzled ds_read): A granule g^(row&7) over 8x16B slots,
//    B granule g^((row>>1)&3) over 4x16B slots -> 2-way bank access (free)
//    instead of the previous ~8-way conflict on both operands.
#define NPASS 64
#define LSEQ  512
#define HDIM  768
#define NSPAN 16
#define MTOT  (NPASS*LSEQ)                     // 32768
#define OFF_SENT (NPASS*HDIM)                  // 49152
#define W_ELEMS (HDIM*HDIM)                    // 589824

#define BM 128
#define BN 128
#define BK 32
#define NK (HDIM/BK)                           // 24 K-iterations

typedef __bf16 bf16x8 __attribute__((ext_vector_type(8)));
typedef __bf16 bf16x4 __attribute__((ext_vector_type(4)));
typedef float  f32x4  __attribute__((ext_vector_type(4)));

__device__ inline unsigned short f2bf(float f) {
  __hip_bfloat16 h = __float2bfloat16(f);   // RNE
  unsigned short u; __builtin_memcpy(&u, &h, 2); return u;
}

// tanh via v_exp_f32: ~7 VALU ops vs ~25 for libm tanhf. |err| < 1e-6 rel,
// far inside the 2% threshold (bf16 input rounding dominates at 6e-3).
__device__ inline float fast_tanh(float x) {
  const float ax = fabsf(x);
  const float t  = __expf(-2.0f * ax);                  // v_exp_f32 path
  const float r  = (1.0f - t) * __builtin_amdgcn_rcpf(1.0f + t);
  return copysignf(r, x);
}

// 8x fp32 -> bf16x8 fragment (RNE via fptrunc; compiler emits cvt_pk pairs).
__device__ inline bf16x8 cvt8(f32x4 lo, f32x4 hi) {
  union { bf16x4 h[2]; bf16x8 v; } u;
  u.h[0] = __builtin_convertvector(lo, bf16x4);
  u.h[1] = __builtin_convertvector(hi, bf16x4);
  return u.v;
}

// fp32 -> bf16 one-shot convert of W only. 8 elems/thread, 16B stores.
__global__ __launch_bounds__(256) void convert_w_kernel(
    const float* __restrict__ W, unsigned short* __restrict__ Wb)
{
  const int i = (blockIdx.x * 256 + threadIdx.x) * 8;
  const float4 a = *(const float4*)(W + i);
  const float4 b = *(const float4*)(W + i + 4);
  union { unsigned short us[8]; uint4 v; } o;
  o.us[0]=f2bf(a.x); o.us[1]=f2bf(a.y); o.us[2]=f2bf(a.z); o.us[3]=f2bf(a.w);
  o.us[4]=f2bf(b.x); o.us[5]=f2bf(b.y); o.us[6]=f2bf(b.z); o.us[7]=f2bf(b.w);
  *(uint4*)(Wb + i) = o.v;
}

// fp32-A x bf16-W NT GEMM + fused tanh/pool epilogue.
// Grid: x = M-tile (256), y = N-tile (6); M fast => same-A blocks same XCD.
__global__ __launch_bounds__(256) void gemm_fused_kernel(
    const float* __restrict__ A,              // (32768, 768) fp32
    const unsigned short* __restrict__ Wb,    // (768, 768) bf16
    const float* __restrict__ bias,
    const int* __restrict__ spans,
    float* __restrict__ out)
{
  __shared__ __align__(16) float          As[2][BM*BK]; // 2 x 16 KB fp32
  __shared__ __align__(16) unsigned short Bs[2][BN*BK]; // 2 x  8 KB bf16
  __shared__ int   sp_st[NSPAN], sp_en[NSPAN];
  __shared__ float inv_s[NSPAN];
  __shared__ short sid_l[BM];      // local row -> span id (-1 none)
  __shared__ float bias_s[BN];

  const int tid  = threadIdx.x;
  const int wave = tid >> 6;
  const int lane = tid & 63;
  const int quad = lane >> 4;
  const int lr   = lane & 15;
  const int wm   = wave >> 1;
  const int wn   = wave & 1;
  const int tile_m = blockIdx.x * BM;
  const int tile_n = blockIdx.y * BN;
  const int npass  = tile_m >> 9;       // passage index
  const int l0     = tile_m & 511;      // first local seq position

  // Stage K-slice k into buffer buf. 24 x 1KB segments (16 A fp32, 8 B bf16),
  // 6 per wave. gload_lds writes LINEAR (lane*16B); the global source granule
  // is pre-swizzled so that LDS(row, g) holds global(row, g ^ f(row)):
  //   A: f(row) = row & 7   (8 x 16B granules per 128 B fp32 row)
  //   B: f(row) = (row>>1)&3 (4 x 16B granules per 64 B bf16 row)
  auto stage = [&](int k, int buf) {
    const int k0 = k * BK;
    #pragma unroll
    for (int j = 0; j < 6; ++j) {
      const int seg = j * 4 + wave;          // wave-uniform 0..23
      if (seg < 16) {
        const int row = seg * 8 + (lane >> 3);
        const int gs  = (lane & 7) ^ ((lane >> 3) & 7);
        const float* g = A + (size_t)(tile_m + row) * HDIM + (k0 + gs * 4);
        __builtin_amdgcn_global_load_lds(
            (const __attribute__((address_space(1))) void*)g,
            (__attribute__((address_space(3))) void*)(As[buf] + seg * 256),
            16, 0, 0);
      } else {
        const int s2  = seg - 16;
        const int row = s2 * 16 + (lane >> 2);
        const int gs  = (lane & 3) ^ ((lane >> 3) & 3);
        const unsigned short* g =
            Wb + (size_t)(tile_n + row) * HDIM + (k0 + gs * 8);
        __builtin_amdgcn_global_load_lds(
            (const __attribute__((address_space(1))) void*)g,
            (__attribute__((address_space(3))) void*)(Bs[buf] + s2 * 512),
            16, 0, 0);
      }
    }
  };

  // Prologue: stage slice 0, fill tables, one barrier covers both.
  stage(0, 0);
  if (tid < NSPAN) {
    const int st = spans[(npass * NSPAN + tid) * 2 + 0];
    const int en = spans[(npass * NSPAN + tid) * 2 + 1];
    sp_st[tid] = st; sp_en[tid] = en; inv_s[tid] = 1.0f / (float)(en - st);
  }
  if (tid >= 128 && tid < 128 + BN) bias_s[tid - 128] = bias[tile_n + tid - 128];
  __syncthreads();
  // sid_l written here, first read in epilogue (after many barriers).
  if (tid < BM) {
    const int l = l0 + tid;
    short s = -1;
    #pragma unroll
    for (int i = 0; i < NSPAN; ++i)
      if (l >= sp_st[i] && l < sp_en[i]) s = (short)i;
    sid_l[tid] = s;
  }

  f32x4 acc[4][4];
  #pragma unroll
  for (int i = 0; i < 4; ++i)
    #pragma unroll
    for (int j = 0; j < 4; ++j)
      acc[i][j] = (f32x4){0.f, 0.f, 0.f, 0.f};

  for (int k = 0; k < NK; ++k) {
    const int cur = k & 1;
    if (k + 1 < NK) stage(k + 1, cur ^ 1);   // prefetch next slice first

    // Fragments: A-operand A[m=lane&15][k=quad*8+j]; B-operand B[k][n=lane&15].
    // Swizzled reads (same XOR as the staged layout) -> 2-way banked (free).
    bf16x8 af[4], bfr[4];
    #pragma unroll
    for (int mt = 0; mt < 4; ++mt) {
      const int r  = wm * 64 + mt * 16 + lr;
      const int sw = r & 7;
      const float* base = As[cur] + r * BK;
      const f32x4 lo = *(const f32x4*)(base + (((quad * 2    ) ^ sw) * 4));
      const f32x4 hi = *(const f32x4*)(base + (((quad * 2 + 1) ^ sw) * 4));
      af[mt] = cvt8(lo, hi);
    }
    #pragma unroll
    for (int nt = 0; nt < 4; ++nt) {
      const int r = wn * 64 + nt * 16 + lr;
      const int g = quad ^ ((r >> 1) & 3);
      bfr[nt] = *(const bf16x8*)(Bs[cur] + (r * BK + g * 8));
    }

    #pragma unroll
    for (int mt = 0; mt < 4; ++mt)
      #pragma unroll
      for (int nt = 0; nt < 4; ++nt)
        acc[mt][nt] = __builtin_amdgcn_mfma_f32_16x16x32_bf16(
            af[mt], bfr[nt], acc[mt][nt], 0, 0, 0);

    // One barrier/iter: (a) everyone done reading buf cur before it's
    // overwritten at k+1; (b) compiler's vmcnt(0) drain covers the prefetch —
    // which has had the whole compute phase to complete.
    __syncthreads();
  }

  // Epilogue. C/D layout: col=lane&15, row=quad*4+reg (R3/R4-validated).
  // Sentence means: run-merged, pre-scaled atomic adds into pre-zeroed out.
  #pragma unroll
  for (int nt = 0; nt < 4; ++nt) {
    const int lcolo = wn * 64 + nt * 16 + lr;       // 0..127
    const int col   = tile_n + lcolo;
    const float bv  = bias_s[lcolo];
    float* sent_col = out + OFF_SENT + (size_t)(npass * NSPAN) * HDIM + col;
    #pragma unroll
    for (int mt = 0; mt < 4; ++mt) {
      const int rowbase = wm * 64 + mt * 16 + quad * 4;  // local row
      int prev = -1; float run = 0.f;
      #pragma unroll
      for (int r = 0; r < 4; ++r) {
        const int lrw = rowbase + r;
        const float v = fast_tanh(acc[mt][nt][r] + bv);
        if (l0 == 0 && lrw == 0) out[(size_t)npass * HDIM + col] = v;
        const int s = sid_l[lrw];
        if (s != prev) {
          if (prev >= 0) unsafeAtomicAdd(sent_col + (size_t)prev * HDIM, run * inv_s[prev]);
          prev = s; run = 0.f;
        }
        run += v;
      }
      if (prev >= 0) unsafeAtomicAdd(sent_col + (size_t)prev * HDIM, run * inv_s[prev]);
    }
  }
}

extern "C" void kernel_launch(void* const* d_in, const int* in_sizes, int n_in,
                              void* d_out, int out_size, void* d_ws, size_t ws_size,
                              hipStream_t stream) {
  const float* hs  = (const float*)d_in[0];  // (64,512,768) fp32
  const float* w   = (const float*)d_in[1];  // (768,768) fp32
  const float* bsc = (const float*)d_in[2];  // (768,) fp32
  // d_in[3] attention_mask unused
  const int* spans = (const int*)d_in[4];    // (64,16,2) int32
  float* out = (float*)d_out;

  unsigned short* Wb = (unsigned short*)d_ws;  // 1,179,648 B

  hipMemsetAsync(d_out, 0, (size_t)out_size * sizeof(float), stream);

  convert_w_kernel<<<dim3(W_ELEMS / 8 / 256), dim3(256), 0, stream>>>(w, Wb);

  dim3 grid(MTOT / BM, HDIM / BN);  // (256, 6): M fast -> A-tile sharers co-XCD
  gemm_fused_kernel<<<grid, dim3(256), 0, stream>>>(hs, Wb, bsc, spans, out);
}